// Round 1
// baseline (289.024 us; speedup 1.0000x reference)
//
#include <hip/hip_runtime.h>

#define N_NODES 50000
#define N_EDGES 600000
#define N_REL 8
#define D_IN 128
#define D_OUT 16
#define EPW 128  // edges per wave in edge kernel

// -------- pass 1: per-(dst, rel) edge counts --------
__global__ __launch_bounds__(256) void count_kernel(const int* __restrict__ ei,
                                                    const int* __restrict__ et,
                                                    int* __restrict__ cnt) {
    int e = blockIdx.x * 256 + threadIdx.x;
    if (e < N_EDGES) {
        int dst = ei[N_EDGES + e];
        int t = et[e];
        atomicAdd(&cnt[dst * N_REL + t], 1);
    }
}

// -------- pass 2: out[n, o] = x[n] @ root[:, o] + bias[o] --------
__global__ __launch_bounds__(256) void init_kernel(const float* __restrict__ x,
                                                   const float* __restrict__ root,
                                                   const float* __restrict__ bias,
                                                   float* __restrict__ out) {
    __shared__ float rootS[D_IN * D_OUT];
    for (int i = threadIdx.x; i < D_IN * D_OUT; i += 256) rootS[i] = root[i];
    __syncthreads();
    int gid = blockIdx.x * 256 + threadIdx.x;
    int n = gid >> 4;
    int o = gid & 15;
    if (n >= N_NODES) return;
    const float4* xr = (const float4*)(x + (size_t)n * D_IN);
    float a0 = 0.f, a1 = 0.f, a2 = 0.f, a3 = 0.f;
#pragma unroll
    for (int d4 = 0; d4 < 32; ++d4) {
        float4 xv = xr[d4];  // same addr across 16 lanes -> HW broadcast
        a0 = fmaf(xv.x, rootS[(d4 * 4 + 0) * D_OUT + o], a0);
        a1 = fmaf(xv.y, rootS[(d4 * 4 + 1) * D_OUT + o], a1);
        a2 = fmaf(xv.z, rootS[(d4 * 4 + 2) * D_OUT + o], a2);
        a3 = fmaf(xv.w, rootS[(d4 * 4 + 3) * D_OUT + o], a3);
    }
    out[gid] = (a0 + a1) + (a2 + a3) + bias[o];
}

// -------- pass 3: per-edge transform + scaled scatter-add --------
// Each wave: one (relation, 128-edge chunk). W_rel column for lane's output
// dim lives in 128 registers. 16 lanes per edge; lane o computes y[o].
__global__ __launch_bounds__(256) void edge_kernel(const float* __restrict__ x,
                                                   const float* __restrict__ W,
                                                   const int* __restrict__ ei,
                                                   const int* __restrict__ eptr,
                                                   const int* __restrict__ cnt,
                                                   float* __restrict__ out) {
    int wid = (blockIdx.x * 256 + threadIdx.x) >> 6;
    int lane = threadIdx.x & 63;
    int o = lane & 15;
    int sub = lane >> 4;

    // map wid -> (rel, chunk) via edge_ptr scan (uniform across wave)
    int rel = -1;
    int chunkStart = 0, relEnd = 0;
    {
        int base = 0;
        int prev = eptr[0];
#pragma unroll
        for (int r = 0; r < N_REL; ++r) {
            int pe = eptr[r + 1];
            int c = (pe - prev + EPW - 1) / EPW;
            if (rel < 0 && wid < base + c) {
                rel = r;
                chunkStart = prev + (wid - base) * EPW;
                relEnd = pe;
            }
            base += c;
            prev = pe;
        }
    }
    if (rel < 0) return;

    // W_rel column o -> 128 registers (coalesced: 16 consecutive x4 per d)
    const float* Wr = W + rel * (D_IN * D_OUT);
    float w[D_IN];
#pragma unroll
    for (int d = 0; d < D_IN; ++d) w[d] = Wr[d * D_OUT + o];

    for (int i = 0; i < EPW; i += 4) {
        int e = chunkStart + i + sub;
        if (e < relEnd) {
            int src = ei[e];
            int dst = ei[N_EDGES + e];
            const float4* xr = (const float4*)(x + (size_t)src * D_IN);
            float a0 = 0.f, a1 = 0.f, a2 = 0.f, a3 = 0.f;
#pragma unroll
            for (int d4 = 0; d4 < 32; ++d4) {
                float4 xv = xr[d4];  // broadcast across the 16-lane subgroup
                a0 = fmaf(xv.x, w[d4 * 4 + 0], a0);
                a1 = fmaf(xv.y, w[d4 * 4 + 1], a1);
                a2 = fmaf(xv.z, w[d4 * 4 + 2], a2);
                a3 = fmaf(xv.w, w[d4 * 4 + 3], a3);
            }
            float c = (float)cnt[dst * N_REL + rel];  // >= 1 (this edge counted)
            float y = ((a0 + a1) + (a2 + a3)) * __builtin_amdgcn_rcpf(c);
            atomicAdd(&out[dst * D_OUT + o], y);
        }
    }
}

extern "C" void kernel_launch(void* const* d_in, const int* in_sizes, int n_in,
                              void* d_out, int out_size, void* d_ws, size_t ws_size,
                              hipStream_t stream) {
    const float* x    = (const float*)d_in[0];
    const float* W    = (const float*)d_in[1];
    const float* root = (const float*)d_in[2];
    const float* bias = (const float*)d_in[3];
    const int* ei     = (const int*)d_in[4];
    const int* et     = (const int*)d_in[5];
    const int* eptr   = (const int*)d_in[6];
    float* out = (float*)d_out;
    int* cnt   = (int*)d_ws;  // N_NODES*N_REL ints = 1.6 MB

    hipMemsetAsync(cnt, 0, (size_t)N_NODES * N_REL * sizeof(int), stream);
    count_kernel<<<(N_EDGES + 255) / 256, 256, 0, stream>>>(ei, et, cnt);
    init_kernel<<<(N_NODES * D_OUT + 255) / 256, 256, 0, stream>>>(x, root, bias, out);
    int waves = (N_EDGES + EPW - 1) / EPW + N_REL;
    int blocks = (waves + 3) / 4;
    edge_kernel<<<blocks, 256, 0, stream>>>(x, W, ei, eptr, cnt, out);
}

// Round 2
// 285.057 us; speedup vs baseline: 1.0139x; 1.0139x over previous
//
#include <hip/hip_runtime.h>

#define N_NODES 50000
#define N_EDGES 600000
#define N_REL 8
#define D_IN 128
#define D_OUT 16
#define EPW 32   // edges per wave (index prefetch: 32 src + 32 dst lanes)
#define NPW 16   // nodes per wave in init path

#define COUNT_BLOCKS ((N_EDGES + 255) / 256)   // 2344
#define INIT_WAVES   (N_NODES / NPW)           // 3125
#define INIT_BLOCKS  ((INIT_WAVES + 3) / 4)    // 782
#define EDGE_WAVES   (N_EDGES / EPW + N_REL)   // 18758 upper bound
#define EDGE_BLOCKS  ((EDGE_WAVES + 3) / 4)    // 4690

// -------- fused prep: per-(dst,rel) counts  +  out = x@root + bias --------
__global__ __launch_bounds__(256) void prep_kernel(const float* __restrict__ x,
                                                   const float* __restrict__ root,
                                                   const float* __restrict__ bias,
                                                   const int* __restrict__ ei,
                                                   const int* __restrict__ et,
                                                   int* __restrict__ cnt,
                                                   float* __restrict__ out) {
    if (blockIdx.x < COUNT_BLOCKS) {
        int e = blockIdx.x * 256 + threadIdx.x;
        if (e < N_EDGES) {
            int dst = ei[N_EDGES + e];
            atomicAdd(&cnt[dst * N_REL + et[e]], 1);
        }
        return;
    }
    int wid = (blockIdx.x - COUNT_BLOCKS) * 4 + (threadIdx.x >> 6);
    if (wid >= INIT_WAVES) return;
    int lane = threadIdx.x & 63;
    int o = lane & 15;   // output dim
    int dg = lane >> 4;  // d-slice [dg*32, dg*32+32)

    // root fragment in 32 registers: w[j] = root[dg*32+j][o]
    const float* rp = root + dg * 32 * D_OUT + o;
    float w[32];
#pragma unroll
    for (int j = 0; j < 32; ++j) w[j] = rp[j * D_OUT];
    float bv = bias[o];

    int n0 = wid * NPW;
    for (int t = 0; t < NPW; ++t) {
        int n = n0 + t;
        const float4* xr = (const float4*)(x + (size_t)n * D_IN + dg * 32);
        float a0 = 0.f, a1 = 0.f, a2 = 0.f, a3 = 0.f;
#pragma unroll
        for (int k = 0; k < 8; ++k) {
            float4 xv = xr[k];
            a0 = fmaf(xv.x, w[4 * k + 0], a0);
            a1 = fmaf(xv.y, w[4 * k + 1], a1);
            a2 = fmaf(xv.z, w[4 * k + 2], a2);
            a3 = fmaf(xv.w, w[4 * k + 3], a3);
        }
        float y = (a0 + a1) + (a2 + a3);
        y += __shfl_xor(y, 16);  // combine dg pairs
        y += __shfl_xor(y, 32);
        if (lane < 16) out[(size_t)n * D_OUT + o] = y + bv;
    }
}

// -------- edge transform + scaled scatter-add --------
// 64 lanes per edge: lane (o, dg); W_rel fragment = 32 regs/lane (no spill).
__global__ __launch_bounds__(256) void edge_kernel(const float* __restrict__ x,
                                                   const float* __restrict__ W,
                                                   const int* __restrict__ ei,
                                                   const int* __restrict__ eptr,
                                                   const int* __restrict__ cnt,
                                                   float* __restrict__ out) {
    int wid = (blockIdx.x * 256 + threadIdx.x) >> 6;
    int lane = threadIdx.x & 63;
    int o = lane & 15;
    int dg = lane >> 4;

    // wid -> (rel, chunk) via edge_ptr scan (uniform across wave)
    int rel = -1, chunkStart = 0, relEnd = 0;
    {
        int base = 0, prev = eptr[0];
#pragma unroll
        for (int r = 0; r < N_REL; ++r) {
            int pe = eptr[r + 1];
            int c = (pe - prev + EPW - 1) / EPW;
            if (rel < 0 && wid < base + c) {
                rel = r;
                chunkStart = prev + (wid - base) * EPW;
                relEnd = pe;
            }
            base += c;
            prev = pe;
        }
    }
    if (rel < 0) return;
    int nE = min(EPW, relEnd - chunkStart);

    // index prefetch: lanes 0..31 load src, lanes 32..63 load dst (one instr)
    int idxv = 0;
    if ((lane & 31) < nE)
        idxv = ei[(lane >> 5) * N_EDGES + (chunkStart + (lane & 31))];
    // inverse mean counts on dst lanes
    float invcv = 0.f;
    if (lane >= 32 && (lane & 31) < nE)
        invcv = __builtin_amdgcn_rcpf((float)cnt[idxv * N_REL + rel]);

    // W fragment in 32 registers: w[j] = W[rel][dg*32+j][o]
    const float* Wr = W + rel * (D_IN * D_OUT) + dg * 32 * D_OUT + o;
    float w[32];
#pragma unroll
    for (int j = 0; j < 32; ++j) w[j] = Wr[j * D_OUT];

    for (int i = 0; i < nE; ++i) {
        // wave-uniform edge metadata -> scalar regs (readlane, i is uniform)
        int src = __builtin_amdgcn_readlane(idxv, i);
        int dst = __builtin_amdgcn_readlane(idxv, 32 + i);
        float invc = __uint_as_float(
            __builtin_amdgcn_readlane(__float_as_uint(invcv), 32 + i));

        const float4* xr = (const float4*)(x + (size_t)src * D_IN + dg * 32);
        float4 xv[8];
#pragma unroll
        for (int k = 0; k < 8; ++k) xv[k] = xr[k];  // 8 independent 16B loads
        float a0 = 0.f, a1 = 0.f, a2 = 0.f, a3 = 0.f;
#pragma unroll
        for (int k = 0; k < 8; ++k) {
            a0 = fmaf(xv[k].x, w[4 * k + 0], a0);
            a1 = fmaf(xv[k].y, w[4 * k + 1], a1);
            a2 = fmaf(xv[k].z, w[4 * k + 2], a2);
            a3 = fmaf(xv[k].w, w[4 * k + 3], a3);
        }
        float y = (a0 + a1) + (a2 + a3);
        y += __shfl_xor(y, 16);  // reduce across dg
        y += __shfl_xor(y, 32);
        if (lane < 16) atomicAdd(&out[(size_t)dst * D_OUT + o], y * invc);
    }
}

extern "C" void kernel_launch(void* const* d_in, const int* in_sizes, int n_in,
                              void* d_out, int out_size, void* d_ws, size_t ws_size,
                              hipStream_t stream) {
    const float* x    = (const float*)d_in[0];
    const float* W    = (const float*)d_in[1];
    const float* root = (const float*)d_in[2];
    const float* bias = (const float*)d_in[3];
    const int* ei     = (const int*)d_in[4];
    const int* et     = (const int*)d_in[5];
    const int* eptr   = (const int*)d_in[6];
    float* out = (float*)d_out;
    int* cnt   = (int*)d_ws;  // N_NODES*N_REL ints = 1.6 MB

    hipMemsetAsync(cnt, 0, (size_t)N_NODES * N_REL * sizeof(int), stream);
    prep_kernel<<<COUNT_BLOCKS + INIT_BLOCKS, 256, 0, stream>>>(x, root, bias, ei, et, cnt, out);
    edge_kernel<<<EDGE_BLOCKS, 256, 0, stream>>>(x, W, ei, eptr, cnt, out);
}

// Round 3
// 254.133 us; speedup vs baseline: 1.1373x; 1.1217x over previous
//
#include <hip/hip_runtime.h>

#define N_NODES 50000
#define N_EDGES 600000
#define N_REL 8
#define D_IN 128
#define D_OUT 16

#define COUNT_BLOCKS ((N_EDGES + 255) / 256)        // 2344
#define GEMM_CHUNKS  (N_NODES / 16)                 // 3125 (16 nodes per wave)
#define GEMM_WAVES   ((N_REL + 1) * GEMM_CHUNKS)    // 28125
#define GEMM_BLOCKS  ((GEMM_WAVES + 3) / 4)         // 7032
#define PREP_BLOCKS  (COUNT_BLOCKS + GEMM_BLOCKS)
#define EDGE_WAVES   (N_EDGES / 64)                 // 9375 (64 edges per wave)
#define EDGE_BLOCKS  ((EDGE_WAVES + 3) / 4)         // 2344

// -------- prep: (a) per-(dst,rel) counts, (b) dense transform --------
// xW[n][g*16+o] = x[n] @ W_g  for g=0..7; out[n][o] = x[n]@root + bias.
// Wave layout: lane=(o,dg), W-column fragment in 32 regs, 16 nodes/wave.
// g = wid % 9 so the 9 groups of one node-chunk are consecutive wids
// (same-ish CU/XCD -> x rows hit L1/L2 on the 8 re-reads).
__global__ __launch_bounds__(256, 4) void prep_kernel(const float* __restrict__ x,
                                                      const float* __restrict__ W,
                                                      const float* __restrict__ root,
                                                      const float* __restrict__ bias,
                                                      const int* __restrict__ ei,
                                                      const int* __restrict__ et,
                                                      int* __restrict__ cnt,
                                                      float* __restrict__ xW,
                                                      float* __restrict__ out) {
    if (blockIdx.x < COUNT_BLOCKS) {
        int e = blockIdx.x * 256 + threadIdx.x;
        if (e < N_EDGES)
            atomicAdd(&cnt[ei[N_EDGES + e] * N_REL + et[e]], 1);
        return;
    }
    int wid = (blockIdx.x - COUNT_BLOCKS) * 4 + (threadIdx.x >> 6);
    if (wid >= GEMM_WAVES) return;
    int lane = threadIdx.x & 63;
    int o = lane & 15;   // output col within group
    int dg = lane >> 4;  // K-slice [dg*32, dg*32+32)
    int g = wid % (N_REL + 1);
    int chunk = wid / (N_REL + 1);

    const float* Wg = (g < N_REL) ? (W + g * (D_IN * D_OUT)) : root;
    const float* wp = Wg + dg * 32 * D_OUT + o;
    float w[32];
#pragma unroll
    for (int j = 0; j < 32; ++j) w[j] = wp[j * D_OUT];
    float bv = (g == N_REL) ? bias[o] : 0.f;

    int n0 = chunk * 16;
    for (int t = 0; t < 16; ++t) {
        int n = n0 + t;
        const float4* xr = (const float4*)(x + (size_t)n * D_IN + dg * 32);
        float a0 = 0.f, a1 = 0.f, a2 = 0.f, a3 = 0.f;
#pragma unroll
        for (int k = 0; k < 8; ++k) {
            float4 xv = xr[k];
            a0 = fmaf(xv.x, w[4 * k + 0], a0);
            a1 = fmaf(xv.y, w[4 * k + 1], a1);
            a2 = fmaf(xv.z, w[4 * k + 2], a2);
            a3 = fmaf(xv.w, w[4 * k + 3], a3);
        }
        float y = (a0 + a1) + (a2 + a3);
        y += __shfl_xor(y, 16);  // reduce across dg
        y += __shfl_xor(y, 32);
        if (lane < 16) {
            if (g < N_REL) xW[(size_t)n * D_IN + g * D_OUT + o] = y;
            else           out[(size_t)n * D_OUT + o] = y + bv;
        }
    }
}

// -------- edge pass: out[dst,o] += xW[src, rel*16+o] / cnt[dst,rel] --------
// 16 lanes per edge (lane o = output dim), 4 edge slots per wave, 16 fully
// unrolled iterations -> 16 independent 64B gathers in flight per wave.
// Atomics are fire-and-forget (no return) -> no wait in the loop.
__global__ __launch_bounds__(256, 4) void edge_kernel(const float* __restrict__ xW,
                                                      const int* __restrict__ ei,
                                                      const int* __restrict__ et,
                                                      const int* __restrict__ cnt,
                                                      float* __restrict__ out) {
    int wid = (blockIdx.x * 256 + threadIdx.x) >> 6;
    if (wid >= EDGE_WAVES) return;
    int lane = threadIdx.x & 63;
    int s = lane >> 4;   // edge slot 0..3
    int o = lane & 15;   // output dim
    int e0 = wid * 64 + s;
#pragma unroll
    for (int i = 0; i < 16; ++i) {
        int e = e0 + i * 4;
        int src = ei[e];              // broadcast across the 16-lane subgroup
        int dst = ei[N_EDGES + e];
        int rel = et[e];
        float c = (float)cnt[dst * N_REL + rel];   // >= 1 (this edge counted)
        float v = xW[(size_t)src * D_IN + rel * D_OUT + o];
        atomicAdd(&out[(size_t)dst * D_OUT + o], v * __builtin_amdgcn_rcpf(c));
    }
}

extern "C" void kernel_launch(void* const* d_in, const int* in_sizes, int n_in,
                              void* d_out, int out_size, void* d_ws, size_t ws_size,
                              hipStream_t stream) {
    const float* x    = (const float*)d_in[0];
    const float* W    = (const float*)d_in[1];
    const float* root = (const float*)d_in[2];
    const float* bias = (const float*)d_in[3];
    const int* ei     = (const int*)d_in[4];
    const int* et     = (const int*)d_in[5];
    float* out = (float*)d_out;

    int* cnt  = (int*)d_ws;                                   // 400000 ints = 1.6 MB
    float* xW = (float*)((char*)d_ws + (size_t)N_NODES * N_REL * sizeof(int));  // 25.6 MB

    hipMemsetAsync(cnt, 0, (size_t)N_NODES * N_REL * sizeof(int), stream);
    prep_kernel<<<PREP_BLOCKS, 256, 0, stream>>>(x, W, root, bias, ei, et, cnt, xW, out);
    edge_kernel<<<EDGE_BLOCKS, 256, 0, stream>>>(xW, ei, et, cnt, out);
}

// Round 4
// 249.364 us; speedup vs baseline: 1.1590x; 1.0191x over previous
//
#include <hip/hip_runtime.h>

#define N_NODES 50000
#define N_EDGES 600000
#define N_REL 8
#define D_IN 128
#define D_OUT 16

#define COUNT_BLOCKS ((N_EDGES + 255) / 256)        // 2344
#define GEMM_CHUNKS  (N_NODES / 16)                 // 3125 (16 nodes per wave)
#define GEMM_WAVES   ((N_REL + 1) * GEMM_CHUNKS)    // 28125
#define GEMM_BLOCKS  ((GEMM_WAVES + 3) / 4)         // 7032
#define PREP_BLOCKS  (COUNT_BLOCKS + GEMM_BLOCKS)
#define EDGE_WAVES   (N_EDGES / 64)                 // 9375 (64 edges per wave)
#define EDGE_BLOCKS  ((EDGE_WAVES + 3) / 4)         // 2344

// Pin a value into a VGPR: opaque def stops invariant-load rematerialization.
#define PIN(v) asm volatile("" : "+v"(v))

// -------- prep: (a) per-(dst,rel) counts, (b) dense transform --------
// xW[n][g*16+o] = x[n] @ W_g  for g=0..7; out[n][o] = x[n]@root + bias.
// Wave layout: lane=(o,dg); W-column fragment PINNED in 32 regs; 16 nodes/wave.
__global__ __launch_bounds__(256, 4) void prep_kernel(const float* __restrict__ x,
                                                      const float* __restrict__ W,
                                                      const float* __restrict__ root,
                                                      const float* __restrict__ bias,
                                                      const int* __restrict__ ei,
                                                      const int* __restrict__ et,
                                                      int* __restrict__ cnt,
                                                      float* __restrict__ xW,
                                                      float* __restrict__ out) {
    if (blockIdx.x < COUNT_BLOCKS) {
        int e = blockIdx.x * 256 + threadIdx.x;
        if (e < N_EDGES)
            atomicAdd(&cnt[ei[N_EDGES + e] * N_REL + et[e]], 1);
        return;
    }
    int wid = (blockIdx.x - COUNT_BLOCKS) * 4 + (threadIdx.x >> 6);
    if (wid >= GEMM_WAVES) return;
    int lane = threadIdx.x & 63;
    int o = lane & 15;   // output col within group
    int dg = lane >> 4;  // K-slice [dg*32, dg*32+32)
    int g = wid % (N_REL + 1);
    int chunk = wid / (N_REL + 1);

    const float* Wg = (g < N_REL) ? (W + g * (D_IN * D_OUT)) : root;
    const float* wp = Wg + dg * 32 * D_OUT + o;
    float w[32];
#pragma unroll
    for (int j = 0; j < 32; ++j) w[j] = wp[j * D_OUT];
#pragma unroll
    for (int j = 0; j < 32; ++j) PIN(w[j]);   // force materialization, once
    float bv = (g == N_REL) ? bias[o] : 0.f;

    int n0 = chunk * 16;
    for (int t = 0; t < 16; ++t) {
        int n = n0 + t;
        const float4* xr = (const float4*)(x + (size_t)n * D_IN + dg * 32);
        float a0 = 0.f, a1 = 0.f, a2 = 0.f, a3 = 0.f;
#pragma unroll
        for (int k = 0; k < 8; ++k) {
            float4 xv = xr[k];
            a0 = fmaf(xv.x, w[4 * k + 0], a0);
            a1 = fmaf(xv.y, w[4 * k + 1], a1);
            a2 = fmaf(xv.z, w[4 * k + 2], a2);
            a3 = fmaf(xv.w, w[4 * k + 3], a3);
        }
        float y = (a0 + a1) + (a2 + a3);
        y += __shfl_xor(y, 16);  // reduce across dg
        y += __shfl_xor(y, 32);
        if (lane < 16) {
            if (g < N_REL) xW[(size_t)n * D_IN + g * D_OUT + o] = y;
            else           out[(size_t)n * D_OUT + o] = y + bv;
        }
    }
}

// -------- edge pass: out[dst,o] += xW[src, rel*16+o] / cnt[dst,rel] --------
// Each of the 4 lane-slots owns 16 CONTIGUOUS edges: indices arrive as 4x int4
// vector loads; offsets + inverse counts precomputed and PINNED so all 16 xW
// gathers fly concurrently; atomics are fire-and-forget.
__global__ __launch_bounds__(256, 4) void edge_kernel(const float* __restrict__ xW,
                                                      const int* __restrict__ ei,
                                                      const int* __restrict__ et,
                                                      const int* __restrict__ cnt,
                                                      float* __restrict__ out) {
    int wid = (blockIdx.x * 256 + threadIdx.x) >> 6;
    if (wid >= EDGE_WAVES) return;
    int lane = threadIdx.x & 63;
    int s = lane >> 4;   // edge slot 0..3
    int o = lane & 15;   // output dim
    int e0 = wid * 64 + s * 16;   // 16 contiguous edges (64B-aligned)

    int srcv[16], dstv[16], relv[16];
#pragma unroll
    for (int k = 0; k < 4; ++k) {
        int4 sv = ((const int4*)(ei + e0))[k];
        int4 dv = ((const int4*)(ei + N_EDGES + e0))[k];
        int4 tv = ((const int4*)(et + e0))[k];
        srcv[4 * k + 0] = sv.x; srcv[4 * k + 1] = sv.y;
        srcv[4 * k + 2] = sv.z; srcv[4 * k + 3] = sv.w;
        dstv[4 * k + 0] = dv.x; dstv[4 * k + 1] = dv.y;
        dstv[4 * k + 2] = dv.z; dstv[4 * k + 3] = dv.w;
        relv[4 * k + 0] = tv.x; relv[4 * k + 1] = tv.y;
        relv[4 * k + 2] = tv.z; relv[4 * k + 3] = tv.w;
    }

    int go[16], oo[16];
    float invc[16];
#pragma unroll
    for (int i = 0; i < 16; ++i) {
        go[i] = srcv[i] * D_IN + relv[i] * D_OUT;   // xW gather offset
        oo[i] = dstv[i] * D_OUT;                    // out offset
    }
#pragma unroll
    for (int i = 0; i < 16; ++i)   // 16 independent cnt gathers
        invc[i] = __builtin_amdgcn_rcpf((float)cnt[dstv[i] * N_REL + relv[i]]);
#pragma unroll
    for (int i = 0; i < 16; ++i) { PIN(go[i]); PIN(oo[i]); PIN(invc[i]); }

    float v[16];
#pragma unroll
    for (int i = 0; i < 16; ++i) v[i] = xW[go[i] + o];  // 16 gathers in flight
#pragma unroll
    for (int i = 0; i < 16; ++i) PIN(v[i]);
#pragma unroll
    for (int i = 0; i < 16; ++i)
        atomicAdd(&out[oo[i] + o], v[i] * invc[i]);
}

extern "C" void kernel_launch(void* const* d_in, const int* in_sizes, int n_in,
                              void* d_out, int out_size, void* d_ws, size_t ws_size,
                              hipStream_t stream) {
    const float* x    = (const float*)d_in[0];
    const float* W    = (const float*)d_in[1];
    const float* root = (const float*)d_in[2];
    const float* bias = (const float*)d_in[3];
    const int* ei     = (const int*)d_in[4];
    const int* et     = (const int*)d_in[5];
    float* out = (float*)d_out;

    int* cnt  = (int*)d_ws;                                   // 400000 ints = 1.6 MB
    float* xW = (float*)((char*)d_ws + (size_t)N_NODES * N_REL * sizeof(int));  // 25.6 MB

    hipMemsetAsync(cnt, 0, (size_t)N_NODES * N_REL * sizeof(int), stream);
    prep_kernel<<<PREP_BLOCKS, 256, 0, stream>>>(x, W, root, bias, ei, et, cnt, xW, out);
    edge_kernel<<<EDGE_BLOCKS, 256, 0, stream>>>(xW, ei, et, cnt, out);
}

// Round 6
// 151.949 us; speedup vs baseline: 1.9021x; 1.6411x over previous
//
#include <hip/hip_runtime.h>

#define N_NODES 50000
#define N_EDGES 600000
#define N_REL 8
#define D_IN 128
#define D_OUT 16
#define NC 144   // 8 relation col-groups + root

typedef __attribute__((ext_vector_type(8))) short bf16x8;
typedef __attribute__((ext_vector_type(4))) float f32x4;
typedef __attribute__((ext_vector_type(8))) unsigned short u16x8;

#define COUNT_BLOCKS  ((N_EDGES + 255) / 256)         // 2344
#define XCONV_BLOCKS  ((N_NODES * D_IN) / (256 * 8))  // 3125 (8 elems/thread)
#define WBUILD_BLOCKS ((NC * D_IN + 255) / 256)       // 72
#define PREP0_BLOCKS  (COUNT_BLOCKS + XCONV_BLOCKS + WBUILD_BLOCKS)
#define GEMM_BLOCKS   ((N_NODES + 63) / 64)           // 782 (64 nodes/block)
#define EDGE_BLOCKS   ((N_EDGES / 64 + 3) / 4)        // 2344

__device__ __forceinline__ unsigned short f2bf(float f) {  // RNE
    unsigned u = __float_as_uint(f);
    return (unsigned short)((u + 0x7FFF + ((u >> 16) & 1)) >> 16);
}
__device__ __forceinline__ float bf2f(unsigned short h) {
    return __uint_as_float((unsigned)h << 16);
}
// LDS swizzle for WallT: row c = byte>>8 (256 B rows); XOR (c&7)<<4 keeps
// 16B alignment, spreads the 16-lane column-slice across 8 bank slots.
__device__ __forceinline__ int swz(int byte) { return byte ^ (((byte >> 8) & 7) << 4); }

// -------- prep0: counts + x->bf16 + WallT build (block-range split) --------
__global__ __launch_bounds__(256) void prep0(const float* __restrict__ x,
                                             const float* __restrict__ W,
                                             const float* __restrict__ root,
                                             const int* __restrict__ ei,
                                             const int* __restrict__ et,
                                             int* __restrict__ cnt,
                                             unsigned short* __restrict__ x_bf,
                                             unsigned short* __restrict__ WallT) {
    int b = blockIdx.x;
    if (b < COUNT_BLOCKS) {
        int e = b * 256 + threadIdx.x;
        if (e < N_EDGES)
            atomicAdd(&cnt[ei[N_EDGES + e] * N_REL + et[e]], 1);
    } else if (b < COUNT_BLOCKS + XCONV_BLOCKS) {
        int t = (b - COUNT_BLOCKS) * 256 + threadIdx.x;  // elems [8t, 8t+8)
        const float4* xin = (const float4*)x + (size_t)t * 2;
        float4 a = xin[0], c = xin[1];
        u16x8 p;
        p[0] = f2bf(a.x); p[1] = f2bf(a.y); p[2] = f2bf(a.z); p[3] = f2bf(a.w);
        p[4] = f2bf(c.x); p[5] = f2bf(c.y); p[6] = f2bf(c.z); p[7] = f2bf(c.w);
        ((u16x8*)x_bf)[t] = p;
    } else {
        // WallT[c][k] = (g<8 ? W[g][k][o] : root[k][o]), c = g*16+o
        int t = (b - COUNT_BLOCKS - XCONV_BLOCKS) * 256 + threadIdx.x;
        if (t < NC * D_IN) {
            int c = t >> 7, k = t & 127;
            int g = c >> 4, o = c & 15;
            float v = (g < N_REL) ? W[(g * D_IN + k) * D_OUT + o]
                                  : root[k * D_OUT + o];
            WallT[t] = f2bf(v);
        }
    }
}

// -------- prep1: MFMA GEMM  [64 nodes/block] x [144 cols] --------
// Per wave: 16-node tile. A-frag: lane holds x_bf[n0+(l&15)][(l>>4)*8+j+32s].
// B-frag from swizzled LDS. C/D: col=lane&15, row=(lane>>4)*4+j (m89 layout).
__global__ __launch_bounds__(256) void prep1(const unsigned short* __restrict__ x_bf,
                                             const unsigned short* __restrict__ WallT,
                                             const float* __restrict__ bias,
                                             unsigned short* __restrict__ xW,
                                             float* __restrict__ out) {
    __shared__ unsigned short wlds[NC * D_IN];  // 36864 B
    {
        const float4* src = (const float4*)WallT;
        for (int i = threadIdx.x; i < NC * D_IN / 8; i += 256)
            *(float4*)((char*)wlds + swz(i * 16)) = src[i];
    }
    __syncthreads();

    int wave = threadIdx.x >> 6, lane = threadIdx.x & 63;
    int n0 = blockIdx.x * 64 + wave * 16;
    if (n0 >= N_NODES) return;
    int col = lane & 15, kg = lane >> 4;

    const char* xrow = (const char*)(x_bf + (size_t)(n0 + col) * D_IN) + kg * 16;
    bf16x8 afr[4];
#pragma unroll
    for (int s = 0; s < 4; ++s) afr[s] = *(const bf16x8*)(xrow + s * 64);
    float bv = bias[col];

#pragma unroll
    for (int ct = 0; ct < 9; ++ct) {
        int c = ct * 16 + col;
        f32x4 acc = {0.f, 0.f, 0.f, 0.f};
#pragma unroll
        for (int s = 0; s < 4; ++s) {
            bf16x8 bfr = *(const bf16x8*)((const char*)wlds +
                                          swz(c * 256 + kg * 16 + s * 64));
            acc = __builtin_amdgcn_mfma_f32_16x16x32_bf16(afr[s], bfr, acc, 0, 0, 0);
        }
        if (ct < 8) {
#pragma unroll
            for (int j = 0; j < 4; ++j)
                xW[(size_t)(n0 + kg * 4 + j) * D_IN + ct * 16 + col] = f2bf(acc[j]);
        } else {
#pragma unroll
            for (int j = 0; j < 4; ++j)
                out[(size_t)(n0 + kg * 4 + j) * D_OUT + col] = acc[j] + bv;
        }
    }
}

// -------- edge: out[dst,o] += bf2f(xW[src, rel*16+o]) / cnt[dst,rel] --------
// 16 lanes/edge; each slot owns 16 contiguous edges; int4 index loads;
// 4-edge chunks keep live regs modest while giving 4 gathers in flight.
__global__ __launch_bounds__(256) void edge_k(const unsigned short* __restrict__ xW,
                                              const int* __restrict__ ei,
                                              const int* __restrict__ et,
                                              const int* __restrict__ cnt,
                                              float* __restrict__ out) {
    int wid = (blockIdx.x * 256 + threadIdx.x) >> 6;
    int lane = threadIdx.x & 63;
    int s = lane >> 4, o = lane & 15;
    int e0 = wid * 64 + s * 16;
    if (e0 >= N_EDGES) return;
#pragma unroll 2
    for (int k = 0; k < 4; ++k) {
        int4 s4 = *(const int4*)(ei + e0 + k * 4);
        int4 d4 = *(const int4*)(ei + N_EDGES + e0 + k * 4);
        int4 r4 = *(const int4*)(et + e0 + k * 4);
        float v0 = bf2f(xW[(size_t)s4.x * D_IN + r4.x * D_OUT + o]);
        float v1 = bf2f(xW[(size_t)s4.y * D_IN + r4.y * D_OUT + o]);
        float v2 = bf2f(xW[(size_t)s4.z * D_IN + r4.z * D_OUT + o]);
        float v3 = bf2f(xW[(size_t)s4.w * D_IN + r4.w * D_OUT + o]);
        float c0 = (float)cnt[d4.x * N_REL + r4.x];
        float c1 = (float)cnt[d4.y * N_REL + r4.y];
        float c2 = (float)cnt[d4.z * N_REL + r4.z];
        float c3 = (float)cnt[d4.w * N_REL + r4.w];
        atomicAdd(&out[(size_t)d4.x * D_OUT + o], v0 * __builtin_amdgcn_rcpf(c0));
        atomicAdd(&out[(size_t)d4.y * D_OUT + o], v1 * __builtin_amdgcn_rcpf(c1));
        atomicAdd(&out[(size_t)d4.z * D_OUT + o], v2 * __builtin_amdgcn_rcpf(c2));
        atomicAdd(&out[(size_t)d4.w * D_OUT + o], v3 * __builtin_amdgcn_rcpf(c3));
    }
}

extern "C" void kernel_launch(void* const* d_in, const int* in_sizes, int n_in,
                              void* d_out, int out_size, void* d_ws, size_t ws_size,
                              hipStream_t stream) {
    const float* x    = (const float*)d_in[0];
    const float* W    = (const float*)d_in[1];
    const float* root = (const float*)d_in[2];
    const float* bias = (const float*)d_in[3];
    const int* ei     = (const int*)d_in[4];
    const int* et     = (const int*)d_in[5];
    float* out = (float*)d_out;

    char* ws = (char*)d_ws;
    int* cnt             = (int*)ws;                     ws += (size_t)N_NODES * N_REL * 4;   // 1.6 MB
    unsigned short* x_bf = (unsigned short*)ws;          ws += (size_t)N_NODES * D_IN * 2;    // 12.8 MB
    unsigned short* xW   = (unsigned short*)ws;          ws += (size_t)N_NODES * D_IN * 2;    // 12.8 MB
    unsigned short* WallT= (unsigned short*)ws;          // 36.9 KB

    hipMemsetAsync(cnt, 0, (size_t)N_NODES * N_REL * 4, stream);
    prep0<<<PREP0_BLOCKS, 256, 0, stream>>>(x, W, root, ei, et, cnt, x_bf, WallT);
    prep1<<<GEMM_BLOCKS, 256, 0, stream>>>(x_bf, WallT, bias, xW, out);
    edge_k<<<EDGE_BLOCKS, 256, 0, stream>>>(xW, ei, et, cnt, out);
}